// Round 16
// baseline (550.714 us; speedup 1.0000x reference)
//
#include <hip/hip_runtime.h>
#include <hip/hip_bf16.h>

typedef __attribute__((ext_vector_type(8))) short bf16x8;
typedef __attribute__((ext_vector_type(4))) float f32x4;
typedef __attribute__((ext_vector_type(16))) float f32x16;
typedef long long i64;

#define NB 32
#define NC 256
#define NN 1024

__device__ __forceinline__ unsigned pack2(float a, float b) {
    __hip_bfloat16 ha = __float2bfloat16(a), hb = __float2bfloat16(b);
    unsigned short ua = *(unsigned short*)&ha, ub = *(unsigned short*)&hb;
    return (unsigned)ua | ((unsigned)ub << 16);
}

__device__ __forceinline__ float bflo(unsigned u) {
    union { unsigned i; float f; } x; x.i = u << 16; return x.f;
}
__device__ __forceinline__ float bfhi(unsigned u) {
    union { unsigned i; float f; } x; x.i = u & 0xffff0000u; return x.f;
}
// 4 floats -> 4 OCP e4m3 bytes (little-endian order a,b,c,d)
__device__ __forceinline__ unsigned fp8x4(float a, float b, float c, float d) {
    int w = __builtin_amdgcn_cvt_pk_fp8_f32(a, b, 0, false);
    w = __builtin_amdgcn_cvt_pk_fp8_f32(c, d, w, true);
    return (unsigned)w;
}

// async global->LDS, 16B per lane; LDS dest = wave-uniform base + lane*16
__device__ __forceinline__ void glds16(const void* g, void* lds) {
    __builtin_amdgcn_global_load_lds(
        (const __attribute__((address_space(1))) unsigned int*)g,
        (__attribute__((address_space(3))) unsigned int*)lds, 16, 0, 0);
}

// ---------------------------------------------------------------------------
// Kernel 1: QKV projection with in-kernel transpose (r15, unchanged).
// ---------------------------------------------------------------------------
__global__ __launch_bounds__(256, 2) void qkv_panel_kernel(
    const float* __restrict__ x, const float* __restrict__ w_in,
    const float* __restrict__ b_in, unsigned char* __restrict__ Qt8,
    unsigned char* __restrict__ Kt8, unsigned char* __restrict__ Vf8)
{
    __shared__ char smem[67584];
    char* const Ap = smem;                  // A-panel, 32 KB
    char* const X0 = smem + 32768;
    char* const X1 = smem + 49152;
    char* const B0 = smem + 32768;
    char* const B1 = smem + 40960;
    __hip_bfloat16* const Ls = (__hip_bfloat16*)(smem + 32768);  // [128][136]

    const int t  = threadIdx.x;
    const int wv = t >> 6, ln = t & 63, lo = ln & 15, hi = ln >> 4;
    const int wm = wv >> 1, wn = wv & 1;
    const int n0 = blockIdx.x * 128, og = blockIdx.y, b = blockIdx.z;
    const float* xb = x + (size_t)b * NC * NN;

    auto xstage = [&](int cc, char* Xd) {
        #pragma unroll
        for (int p2 = 0; p2 < 4; ++p2) {
            const int idx = p2 * 256 + t;
            const int r = idx >> 5, u = idx & 31;
            glds16(xb + (size_t)(cc * 32 + r) * NN + n0 + u * 4, Xd + idx * 16);
        }
    };
    const int tn = t & 127, thalf = t >> 7;
    auto xpose_chunk = [&](int cc, const char* Xd) {
        const float* Xf = (const float*)Xd;
        float v[16];
        #pragma unroll
        for (int j = 0; j < 16; ++j) v[j] = Xf[(thalf * 16 + j) * 128 + tn];
        uint4 pk;
        pk.x = fp8x4(v[0],  v[1],  v[2],  v[3]);
        pk.y = fp8x4(v[4],  v[5],  v[6],  v[7]);
        pk.z = fp8x4(v[8],  v[9],  v[10], v[11]);
        pk.w = fp8x4(v[12], v[13], v[14], v[15]);
        const int m = cc * 2 + thalf;
        *(uint4*)(Ap + tn * 256 + (m ^ (tn & 7)) * 16) = pk;
    };

    xstage(0, X0);
    __syncthreads();
    for (int cc = 0; cc < 8; ++cc) {
        char* cur = (cc & 1) ? X1 : X0;
        if (cc < 7) xstage(cc + 1, (cc & 1) ? X0 : X1);
        xpose_chunk(cc, cur);
        __syncthreads();
    }

    auto bstage = [&](int ot, int ks, char* Bd) {
        #pragma unroll
        for (int p2 = 0; p2 < 2; ++p2) {
            const int idx = p2 * 256 + t;
            const int row = idx >> 2, pc = idx & 3;
            const int lp = pc ^ (row & 3);
            const float* wp = w_in + (size_t)(ot * 128 + row) * NC + ks * 64 + lp * 16;
            const float4 u0 = *(const float4*)wp;
            const float4 u1 = *(const float4*)(wp + 4);
            const float4 u2 = *(const float4*)(wp + 8);
            const float4 u3 = *(const float4*)(wp + 12);
            uint4 pk;
            pk.x = fp8x4(u0.x, u0.y, u0.z, u0.w);
            pk.y = fp8x4(u1.x, u1.y, u1.z, u1.w);
            pk.z = fp8x4(u2.x, u2.y, u2.z, u2.w);
            pk.w = fp8x4(u3.x, u3.y, u3.z, u3.w);
            *(uint4*)(Bd + idx * 16) = pk;
        }
    };

    int ra[4], rb[4];
    #pragma unroll
    for (int f = 0; f < 4; ++f) { ra[f] = wm * 64 + f * 16 + lo; rb[f] = wn * 64 + f * 16 + lo; }

    for (int ot3 = 0; ot3 < 3; ++ot3) {
        const int ot = og * 3 + ot3;
        const int o0 = ot * 128;

        f32x4 acc[4][4];
        #pragma unroll
        for (int i = 0; i < 4; ++i)
            #pragma unroll
            for (int j = 0; j < 4; ++j) acc[i][j] = (f32x4){0.f, 0.f, 0.f, 0.f};

        bstage(ot, 0, B0);
        __syncthreads();
        #pragma unroll
        for (int ks = 0; ks < 4; ++ks) {
            char* Bc = (ks & 1) ? B1 : B0;
            if (ks < 3) bstage(ot, ks + 1, (ks & 1) ? B0 : B1);
            #pragma unroll
            for (int kk = 0; kk < 2; ++kk) {
                const int c8 = (kk << 2) | hi;
                const int m16 = ks * 4 + (c8 >> 1), h8 = c8 & 1;
                i64 av[4], bv[4];
                #pragma unroll
                for (int f = 0; f < 4; ++f) {
                    av[f] = *(const i64*)(Ap + ra[f] * 256 + ((m16 ^ (ra[f] & 7)) * 16) + h8 * 8);
                    bv[f] = *(const i64*)(Bc + rb[f] * 64 + ((c8 ^ ((rb[f] & 3) << 1))) * 8);
                }
                #pragma unroll
                for (int fm = 0; fm < 4; ++fm)
                    #pragma unroll
                    for (int fn = 0; fn < 4; ++fn)
                        acc[fm][fn] = __builtin_amdgcn_mfma_f32_16x16x32_fp8_fp8(
                            av[fm], bv[fn], acc[fm][fn], 0, 0, 0);
            }
            __syncthreads();
        }

        float bias[4];
        #pragma unroll
        for (int fn = 0; fn < 4; ++fn) bias[fn] = b_in[o0 + wn * 64 + fn * 16 + lo];

        if (o0 < 512) {
            #pragma unroll
            for (int fm = 0; fm < 4; ++fm)
                #pragma unroll
                for (int fn = 0; fn < 4; ++fn)
                    #pragma unroll
                    for (int r = 0; r < 4; ++r)
                        Ls[(wm * 64 + fm * 16 + hi * 4 + r) * 136 + wn * 64 + fn * 16 + lo] =
                            __float2bfloat16(acc[fm][fn][r] + bias[fn]);
            __syncthreads();
            unsigned char* dst = (o0 < 256) ? Qt8 : Kt8;
            const int oc = (o0 < 256) ? o0 : o0 - 256;
            #pragma unroll
            for (int p = 0; p < 4; ++p) {
                const int idx = p * 256 + t, row = idx >> 3, ch = idx & 7;
                const unsigned* ls = (const unsigned*)&Ls[row * 136 + ch * 16];
                const uint4 a = *(const uint4*)ls;
                const uint4 b2 = *(const uint4*)(ls + 4);
                uint4 o;
                o.x = fp8x4(bflo(a.x), bfhi(a.x), bflo(a.y), bfhi(a.y));
                o.y = fp8x4(bflo(a.z), bfhi(a.z), bflo(a.w), bfhi(a.w));
                o.z = fp8x4(bflo(b2.x), bfhi(b2.x), bflo(b2.y), bfhi(b2.y));
                o.w = fp8x4(bflo(b2.z), bfhi(b2.z), bflo(b2.w), bfhi(b2.w));
                *(uint4*)(dst + ((size_t)b * NN + n0 + row) * 256 + oc + ch * 16) = o;
            }
        } else {
            #pragma unroll
            for (int fm = 0; fm < 4; ++fm)
                #pragma unroll
                for (int fn = 0; fn < 4; ++fn)
                    #pragma unroll
                    for (int r = 0; r < 4; ++r)
                        Ls[(wn * 64 + fn * 16 + lo) * 136 + wm * 64 + fm * 16 + hi * 4 + r] =
                            __float2bfloat16(acc[fm][fn][r] + bias[fn]);
            __syncthreads();
            #pragma unroll
            for (int p = 0; p < 8; ++p) {
                const int idx = p * 256 + t;
                const int ch = idx >> 7, cr = idx & 127;
                const unsigned* ls = (const unsigned*)&Ls[cr * 136 + ch * 8];
                const uint4 a = *(const uint4*)ls;
                uint2 o;
                o.x = fp8x4(bflo(a.x), bfhi(a.x), bflo(a.y), bfhi(a.y));
                o.y = fp8x4(bflo(a.z), bfhi(a.z), bflo(a.w), bfhi(a.w));
                const int g = (n0 >> 3) + ch;
                *(uint2*)(Vf8 + (((size_t)b * 128 + g) * 256 + (o0 - 512) + cr) * 8) = o;
            }
        }
        __syncthreads();
    }
}

// ---------------------------------------------------------------------------
// Kernel 2: flash attention — 80 KB footprint => 2 blocks/CU (4 waves/SIMD).
// Loop: r11-proven schedule, K ring 4x8K @0, V ring 4x8K @32768 (64 KB);
//   stage tiles 2s+2,2s+3 (1-ahead, disjoint slots from 2s,2s+1), compute
//   tile 2s+half, __syncthreads (drains vmcnt) per step.
// Epilogue (all K/V dead after post-loop sync; budget 81920 B):
//   ex @0       : 64 slots x 132 f32 = 33792 B  (merge, 4 phases of 1 qgrp)
//   Hq @49152   : fp8 H [128 n][256 B], unit swizzle phys16 = u ^ (n&7)
//   Wld @0      : fp8 W_out half [128 o][256 B], same swizzle (overlays ex)
//   out-GEMM fp8: D = mfma(Hq_frag, W_frag): lane l32 = o, regs = n-map;
//   store float4 (+bias+x). n-map: j + 8*rq + 4*h2 (verified convention).
// ---------------------------------------------------------------------------
__device__ __forceinline__ void stage_tile(const unsigned char* __restrict__ Kb,
                                           const unsigned char* __restrict__ Vb,
                                           char* Kd, char* Vd, int m0, int t)
{
    {   // K: 512 x 16B units, 1 per thread
        const int row = t >> 4, pc = t & 15;
        const int prow = (row & 19) | ((row & 4) << 1) | ((row & 8) >> 1); // pi
        const int sc = pc ^ (row & 15);
        glds16(Kb + (size_t)(m0 + prow) * 256 + sc * 16, Kd + t * 16);
    }
    {   // V: pure linear 8KB copy
        glds16(Vb + (size_t)(m0 >> 3) * 2048 + t * 16, Vd + t * 16);
    }
}

__global__ __launch_bounds__(512, 4) void attn_kernel(
    const unsigned char* __restrict__ Qt8, const unsigned char* __restrict__ Kt8,
    const unsigned char* __restrict__ Vf8, const float* __restrict__ w_out,
    const float* __restrict__ b_out, const float* __restrict__ xg,
    float* __restrict__ out)
{
    __shared__ char smem[81920];   // = 160K/2 exactly -> 2 blocks/CU

    const int t  = threadIdx.x;
    const int wv = t >> 6, ln = t & 63;
    const int l32 = ln & 31, h2 = ln >> 5;
    const int qgrp = wv & 3, half = wv >> 2;
    const int wid = blockIdx.x + 8 * blockIdx.y;
    const int swz = (wid & 7) * 32 + (wid >> 3);       // XCD gets 4 batches
    const int qb = swz & 7, b = swz >> 3;
    const int n0 = qb * 128;
    const float scale = 0.0625f;  // 1/sqrt(256)

    const unsigned char* Kbase = Kt8 + (size_t)b * NN * 256;
    const unsigned char* Vbase = Vf8 + (size_t)b * 128 * 2048;

    const unsigned char* qp = Qt8 + ((size_t)b * NN + n0 + qgrp * 32 + l32) * 256;
    i64 qf[16];
    #pragma unroll
    for (int ks = 0; ks < 16; ++ks)
        qf[ks] = *(const i64*)(qp + ks * 16 + h2 * 8);

    f32x16 acc[8];
    #pragma unroll
    for (int ct = 0; ct < 8; ++ct)
        #pragma unroll
        for (int r = 0; r < 16; ++r) acc[ct][r] = 0.f;
    float mr = 0.f;
    float sr = 0.f;

    // prologue: stage tiles 0,1 (slots 0,1)
    stage_tile(Kbase, Vbase, smem, smem + 32768, 0, t);
    stage_tile(Kbase, Vbase, smem + 8192, smem + 32768 + 8192, 32, t);
    __syncthreads();

    for (int s = 0; s < 16; ++s) {
        if (s < 15) {
            const int t2 = 2 * s + 2, t3 = 2 * s + 3;
            stage_tile(Kbase, Vbase, smem + (t2 & 3) * 8192,
                       smem + 32768 + (t2 & 3) * 8192, t2 * 32, t);
            stage_tile(Kbase, Vbase, smem + (t3 & 3) * 8192,
                       smem + 32768 + (t3 & 3) * 8192, t3 * 32, t);
        }
        const int tile = 2 * s + half;
        char* const Kc = smem + (tile & 3) * 8192;
        char* const Vc = smem + 32768 + (tile & 3) * 8192;

        // QK(s): two independent 8-deep chains (fp8, K=16)
        f32x16 sfA, sfB;
        #pragma unroll
        for (int r = 0; r < 16; ++r) { sfA[r] = 0.f; sfB[r] = 0.f; }
        __builtin_amdgcn_s_setprio(1);
        #pragma unroll
        for (int ks = 0; ks < 8; ++ks) {
            const int pc = ks ^ (l32 & 15);
            const i64 kf = *(const i64*)(Kc + l32 * 256 + pc * 16 + h2 * 8);
            sfA = __builtin_amdgcn_mfma_f32_32x32x16_fp8_fp8(kf, qf[ks], sfA, 0, 0, 0);
        }
        #pragma unroll
        for (int ks = 8; ks < 16; ++ks) {
            const int pc = ks ^ (l32 & 15);
            const i64 kf = *(const i64*)(Kc + l32 * 256 + pc * 16 + h2 * 8);
            sfB = __builtin_amdgcn_mfma_f32_32x32x16_fp8_fp8(kf, qf[ks], sfB, 0, 0, 0);
        }
        __builtin_amdgcn_s_setprio(0);

        // softmax(s)
        float sv[16];
        #pragma unroll
        for (int r = 0; r < 16; ++r) sv[r] = sfA[r] + sfB[r];

        float m0a = fmaxf(sv[0], sv[1]),  m1a = fmaxf(sv[2], sv[3]);
        float m2a = fmaxf(sv[4], sv[5]),  m3a = fmaxf(sv[6], sv[7]);
        float m4a = fmaxf(sv[8], sv[9]),  m5a = fmaxf(sv[10], sv[11]);
        float m6a = fmaxf(sv[12], sv[13]), m7a = fmaxf(sv[14], sv[15]);
        float m0b = fmaxf(m0a, m1a), m1b = fmaxf(m2a, m3a);
        float m2b = fmaxf(m4a, m5a), m3b = fmaxf(m6a, m7a);
        float tm = fmaxf(fmaxf(m0b, m1b), fmaxf(m2b, m3b));
        tm = fmaxf(tm, __shfl_xor(tm, 32, 64));
        tm *= scale;
        if (__any(tm > mr + 8.f)) {
            const float mn = fmaxf(mr, tm);
            const float al = __expf(mr - mn);
            mr = mn;
            sr *= al;
            #pragma unroll
            for (int ct = 0; ct < 8; ++ct)
                #pragma unroll
                for (int r = 0; r < 16; ++r) acc[ct][r] *= al;
        }
        float p[16];
        #pragma unroll
        for (int r = 0; r < 16; ++r)
            p[r] = __expf(sv[r] * scale - mr);
        float s0a = p[0] + p[1],  s1a = p[2] + p[3];
        float s2a = p[4] + p[5],  s3a = p[6] + p[7];
        float s4a = p[8] + p[9],  s5a = p[10] + p[11];
        float s6a = p[12] + p[13], s7a = p[14] + p[15];
        float sacc = ((s0a + s1a) + (s2a + s3a)) + ((s4a + s5a) + (s6a + s7a));
        sacc += __shfl_xor(sacc, 32, 64);
        sr += sacc;

        // zero-shuffle PV B-frags (pi property)
        i64 pb[2];
        #pragma unroll
        for (int kstep = 0; kstep < 2; ++kstep) {
            union { unsigned u[2]; i64 l; } uu;
            uu.u[0] = fp8x4(p[8 * kstep + 0], p[8 * kstep + 1],
                            p[8 * kstep + 2], p[8 * kstep + 3]);
            uu.u[1] = fp8x4(p[8 * kstep + 4], p[8 * kstep + 5],
                            p[8 * kstep + 6], p[8 * kstep + 7]);
            pb[kstep] = uu.l;
        }

        // PV(s)
        __builtin_amdgcn_s_setprio(1);
        #pragma unroll
        for (int ct = 0; ct < 8; ++ct) {
            #pragma unroll
            for (int kstep = 0; kstep < 2; ++kstep) {
                const i64 vf = *(const i64*)(Vc + (2 * kstep + h2) * 2048 +
                                             (ct * 32 + l32) * 8);
                acc[ct] = __builtin_amdgcn_mfma_f32_32x32x16_fp8_fp8(vf, pb[kstep], acc[ct], 0, 0, 0);
            }
        }
        __builtin_amdgcn_s_setprio(0);
        __syncthreads();  // drains vmcnt: staged tiles resident; slots reusable
    }

    // ---- pair merge (4 phases of one qgrp) -> Hq fp8 in LDS ----
    float* const ex = (float*)smem;                 // 64 slots x 132 f32
    char* const Hq = smem + 49152;                  // fp8 H [128][256B] swizzled
    #pragma unroll
    for (int ph = 0; ph < 4; ++ph) {
        if (half == 1 && qgrp == ph) {
            float* dst = ex + (size_t)ln * 132;
            #pragma unroll
            for (int ct = 0; ct < 8; ++ct)
                #pragma unroll
                for (int rr = 0; rr < 4; ++rr) {
                    f32x4 v = {acc[ct][rr * 4 + 0], acc[ct][rr * 4 + 1],
                               acc[ct][rr * 4 + 2], acc[ct][rr * 4 + 3]};
                    *(f32x4*)(dst + ct * 16 + rr * 4) = v;
                }
            dst[128] = mr;
            dst[129] = sr;
        }
        __syncthreads();
        if (half == 0 && qgrp == ph) {
            const float* src = ex + (size_t)ln * 132;
            const float mb = src[128], lb = src[129];
            const float m = fmaxf(mr, mb);
            float fa = __expf(mr - m), fb = __expf(mb - m);
            const float inv = 1.0f / (sr * fa + lb * fb);
            fa *= inv; fb *= inv;
            const int n = qgrp * 32 + l32;
            char* const hrow = Hq + (size_t)n * 256;
            #pragma unroll
            for (int ct = 0; ct < 8; ++ct)
                #pragma unroll
                for (int ss = 0; ss < 4; ++ss) {
                    const float o0 = acc[ct][ss * 4 + 0] * fa + src[ct * 16 + ss * 4 + 0] * fb;
                    const float o1 = acc[ct][ss * 4 + 1] * fa + src[ct * 16 + ss * 4 + 1] * fb;
                    const float o2 = acc[ct][ss * 4 + 2] * fa + src[ct * 16 + ss * 4 + 2] * fb;
                    const float o3 = acc[ct][ss * 4 + 3] * fa + src[ct * 16 + ss * 4 + 3] * fb;
                    const int u = ct * 2 + (ss >> 1);
                    *(unsigned*)(hrow + (u ^ (n & 7)) * 16 + (ss & 1) * 8 + h2 * 4) =
                        fp8x4(o0, o1, o2, o3);
                }
        }
        __syncthreads();
    }

    // ---- fused output projection (fp8): out = W_out * H^T + b_out + x ----
    char* const Wld = smem;   // fp8 W half [128 o][256B] swizzled, over ex
    #pragma unroll
    for (int oh = 0; oh < 2; ++oh) {
        #pragma unroll
        for (int p = 0; p < 4; ++p) {
            const int idx = p * 512 + t;
            const int o = idx >> 4, m = idx & 15;
            const float* wp = w_out + (size_t)(oh * 128 + o) * NC + m * 16;
            const float4 u0 = *(const float4*)wp;
            const float4 u1 = *(const float4*)(wp + 4);
            const float4 u2 = *(const float4*)(wp + 8);
            const float4 u3 = *(const float4*)(wp + 12);
            uint4 pk;
            pk.x = fp8x4(u0.x, u0.y, u0.z, u0.w);
            pk.y = fp8x4(u1.x, u1.y, u1.z, u1.w);
            pk.z = fp8x4(u2.x, u2.y, u2.z, u2.w);
            pk.w = fp8x4(u3.x, u3.y, u3.z, u3.w);
            *(uint4*)(Wld + (size_t)o * 256 + ((m ^ (o & 7)) * 16)) = pk;
        }
        __syncthreads();

        #pragma unroll
        for (int it = 0; it < 2; ++it) {
            const int tidx = wv * 2 + it;
            const int og2 = tidx >> 2, ng = tidx & 3;
            const int nrow = ng * 32 + l32, orow = og2 * 32 + l32;

            f32x16 oc;
            #pragma unroll
            for (int r = 0; r < 16; ++r) oc[r] = 0.f;
            __builtin_amdgcn_s_setprio(1);
            #pragma unroll
            for (int ks = 0; ks < 16; ++ks) {
                const i64 av = *(const i64*)(Hq + (size_t)nrow * 256 +
                                             ((ks ^ (nrow & 7)) * 16) + h2 * 8);
                const i64 bv = *(const i64*)(Wld + (size_t)orow * 256 +
                                             ((ks ^ (orow & 7)) * 16) + h2 * 8);
                oc = __builtin_amdgcn_mfma_f32_32x32x16_fp8_fp8(av, bv, oc, 0, 0, 0);
            }
            __builtin_amdgcn_s_setprio(0);

            const int o_glob = oh * 128 + og2 * 32 + l32;
            const float bo = b_out[o_glob];
            const size_t rowg = ((size_t)b * NC + o_glob) * NN + n0;
            #pragma unroll
            for (int rq = 0; rq < 4; ++rq) {
                const int nn = ng * 32 + rq * 8 + h2 * 4;
                const float4 xv = *(const float4*)(xg + rowg + nn);
                float4 ov;
                ov.x = oc[rq * 4 + 0] + bo + xv.x;
                ov.y = oc[rq * 4 + 1] + bo + xv.y;
                ov.z = oc[rq * 4 + 2] + bo + xv.z;
                ov.w = oc[rq * 4 + 3] + bo + xv.w;
                *(float4*)(out + rowg + nn) = ov;
            }
        }
        __syncthreads();   // Wld reads done before next half overwrites
    }
}

// ---------------------------------------------------------------------------
extern "C" void kernel_launch(void* const* d_in, const int* in_sizes, int n_in,
                              void* d_out, int out_size, void* d_ws, size_t ws_size,
                              hipStream_t stream) {
    const float* x     = (const float*)d_in[0];
    const float* w_in  = (const float*)d_in[1];
    const float* b_in  = (const float*)d_in[2];
    const float* w_out = (const float*)d_in[3];
    const float* b_out = (const float*)d_in[4];
    float* out = (float*)d_out;

    if (ws_size < (size_t)24 * 1024 * 1024) return;  // fail loud
    char* ws = (char*)d_ws;
    unsigned char* Qt8 = (unsigned char*)(ws);                       // 8 MB
    unsigned char* Kt8 = (unsigned char*)(ws + ((size_t)8 << 20));   // 8 MB
    unsigned char* Vf8 = (unsigned char*)(ws + ((size_t)16 << 20));  // 8 MB

    qkv_panel_kernel<<<dim3(8, 2, 32), 256, 0, stream>>>(x, w_in, b_in, Qt8, Kt8, Vf8);
    attn_kernel<<<dim3(8, 32), 512, 0, stream>>>(Qt8, Kt8, Vf8, w_out, b_out, x, out);
}

// Round 17
// 83.749 us; speedup vs baseline: 6.5758x; 6.5758x over previous
//
#include <hip/hip_runtime.h>
#include <hip/hip_bf16.h>

typedef __attribute__((ext_vector_type(8))) short bf16x8;
typedef __attribute__((ext_vector_type(4))) float f32x4;
typedef __attribute__((ext_vector_type(16))) float f32x16;
typedef long long i64;

#define NB 32
#define NC 256
#define NN 1024

__device__ __forceinline__ unsigned pack2(float a, float b) {
    __hip_bfloat16 ha = __float2bfloat16(a), hb = __float2bfloat16(b);
    unsigned short ua = *(unsigned short*)&ha, ub = *(unsigned short*)&hb;
    return (unsigned)ua | ((unsigned)ub << 16);
}

__device__ __forceinline__ float bflo(unsigned u) {
    union { unsigned i; float f; } x; x.i = u << 16; return x.f;
}
__device__ __forceinline__ float bfhi(unsigned u) {
    union { unsigned i; float f; } x; x.i = u & 0xffff0000u; return x.f;
}
// 4 floats -> 4 OCP e4m3 bytes (little-endian order a,b,c,d)
__device__ __forceinline__ unsigned fp8x4(float a, float b, float c, float d) {
    int w = __builtin_amdgcn_cvt_pk_fp8_f32(a, b, 0, false);
    w = __builtin_amdgcn_cvt_pk_fp8_f32(c, d, w, true);
    return (unsigned)w;
}

// async global->LDS, 16B per lane; LDS dest = wave-uniform base + lane*16
__device__ __forceinline__ void glds16(const void* g, void* lds) {
    __builtin_amdgcn_global_load_lds(
        (const __attribute__((address_space(1))) unsigned int*)g,
        (__attribute__((address_space(3))) unsigned int*)lds, 16, 0, 0);
}

// ---------------------------------------------------------------------------
// Kernel 1: QKV projection with IN-KERNEL transpose (r15, proven).
// Phase 1 (once per block): build A-panel [128 n][256 c] fp8 in LDS.
// Phase 2: 3 o-tile GEMMs off the shared panel; B staged per tile.
// grid (8 n, 2 og, 32 b) = 512 blocks, 2/CU @ 67584B LDS.
// ---------------------------------------------------------------------------
__global__ __launch_bounds__(256, 2) void qkv_panel_kernel(
    const float* __restrict__ x, const float* __restrict__ w_in,
    const float* __restrict__ b_in, unsigned char* __restrict__ Qt8,
    unsigned char* __restrict__ Kt8, unsigned char* __restrict__ Vf8)
{
    __shared__ char smem[67584];
    char* const Ap = smem;                  // A-panel, 32 KB
    char* const X0 = smem + 32768;
    char* const X1 = smem + 49152;
    char* const B0 = smem + 32768;
    char* const B1 = smem + 40960;
    __hip_bfloat16* const Ls = (__hip_bfloat16*)(smem + 32768);  // [128][136]

    const int t  = threadIdx.x;
    const int wv = t >> 6, ln = t & 63, lo = ln & 15, hi = ln >> 4;
    const int wm = wv >> 1, wn = wv & 1;
    const int n0 = blockIdx.x * 128, og = blockIdx.y, b = blockIdx.z;
    const float* xb = x + (size_t)b * NC * NN;

    // ---- Phase 1: A-panel build ----
    auto xstage = [&](int cc, char* Xd) {
        #pragma unroll
        for (int p2 = 0; p2 < 4; ++p2) {
            const int idx = p2 * 256 + t;
            const int r = idx >> 5, u = idx & 31;
            glds16(xb + (size_t)(cc * 32 + r) * NN + n0 + u * 4, Xd + idx * 16);
        }
    };
    const int tn = t & 127, thalf = t >> 7;   // transpose role: n, 16-c half
    auto xpose_chunk = [&](int cc, const char* Xd) {
        const float* Xf = (const float*)Xd;
        float v[16];
        #pragma unroll
        for (int j = 0; j < 16; ++j) v[j] = Xf[(thalf * 16 + j) * 128 + tn];
        uint4 pk;
        pk.x = fp8x4(v[0],  v[1],  v[2],  v[3]);
        pk.y = fp8x4(v[4],  v[5],  v[6],  v[7]);
        pk.z = fp8x4(v[8],  v[9],  v[10], v[11]);
        pk.w = fp8x4(v[12], v[13], v[14], v[15]);
        const int m = cc * 2 + thalf;
        *(uint4*)(Ap + tn * 256 + (m ^ (tn & 7)) * 16) = pk;
    };

    xstage(0, X0);
    __syncthreads();
    for (int cc = 0; cc < 8; ++cc) {
        char* cur = (cc & 1) ? X1 : X0;
        if (cc < 7) xstage(cc + 1, (cc & 1) ? X0 : X1);
        xpose_chunk(cc, cur);
        __syncthreads();   // drains vmcnt (next chunk resident) + ds_writes
    }

    // ---- Phase 2: 3 o-tile GEMMs off the panel ----
    auto bstage = [&](int ot, int ks, char* Bd) {
        #pragma unroll
        for (int p2 = 0; p2 < 2; ++p2) {
            const int idx = p2 * 256 + t;
            const int row = idx >> 2, pc = idx & 3;
            const int lp = pc ^ (row & 3);
            const float* wp = w_in + (size_t)(ot * 128 + row) * NC + ks * 64 + lp * 16;
            const float4 u0 = *(const float4*)wp;
            const float4 u1 = *(const float4*)(wp + 4);
            const float4 u2 = *(const float4*)(wp + 8);
            const float4 u3 = *(const float4*)(wp + 12);
            uint4 pk;
            pk.x = fp8x4(u0.x, u0.y, u0.z, u0.w);
            pk.y = fp8x4(u1.x, u1.y, u1.z, u1.w);
            pk.z = fp8x4(u2.x, u2.y, u2.z, u2.w);
            pk.w = fp8x4(u3.x, u3.y, u3.z, u3.w);
            *(uint4*)(Bd + idx * 16) = pk;
        }
    };

    int ra[4], rb[4];
    #pragma unroll
    for (int f = 0; f < 4; ++f) { ra[f] = wm * 64 + f * 16 + lo; rb[f] = wn * 64 + f * 16 + lo; }

    for (int ot3 = 0; ot3 < 3; ++ot3) {
        const int ot = og * 3 + ot3;
        const int o0 = ot * 128;

        f32x4 acc[4][4];
        #pragma unroll
        for (int i = 0; i < 4; ++i)
            #pragma unroll
            for (int j = 0; j < 4; ++j) acc[i][j] = (f32x4){0.f, 0.f, 0.f, 0.f};

        bstage(ot, 0, B0);
        __syncthreads();
        #pragma unroll
        for (int ks = 0; ks < 4; ++ks) {
            char* Bc = (ks & 1) ? B1 : B0;
            if (ks < 3) bstage(ot, ks + 1, (ks & 1) ? B0 : B1);
            #pragma unroll
            for (int kk = 0; kk < 2; ++kk) {
                const int c8 = (kk << 2) | hi;
                const int m16 = ks * 4 + (c8 >> 1), h8 = c8 & 1;
                i64 av[4], bv[4];
                #pragma unroll
                for (int f = 0; f < 4; ++f) {
                    av[f] = *(const i64*)(Ap + ra[f] * 256 + ((m16 ^ (ra[f] & 7)) * 16) + h8 * 8);
                    bv[f] = *(const i64*)(Bc + rb[f] * 64 + ((c8 ^ ((rb[f] & 3) << 1))) * 8);
                }
                #pragma unroll
                for (int fm = 0; fm < 4; ++fm)
                    #pragma unroll
                    for (int fn = 0; fn < 4; ++fn)
                        acc[fm][fn] = __builtin_amdgcn_mfma_f32_16x16x32_fp8_fp8(
                            av[fm], bv[fn], acc[fm][fn], 0, 0, 0);
            }
            __syncthreads();
        }

        float bias[4];
        #pragma unroll
        for (int fn = 0; fn < 4; ++fn) bias[fn] = b_in[o0 + wn * 64 + fn * 16 + lo];

        if (o0 < 512) {
            #pragma unroll
            for (int fm = 0; fm < 4; ++fm)
                #pragma unroll
                for (int fn = 0; fn < 4; ++fn)
                    #pragma unroll
                    for (int r = 0; r < 4; ++r)
                        Ls[(wm * 64 + fm * 16 + hi * 4 + r) * 136 + wn * 64 + fn * 16 + lo] =
                            __float2bfloat16(acc[fm][fn][r] + bias[fn]);
            __syncthreads();
            unsigned char* dst = (o0 < 256) ? Qt8 : Kt8;
            const int oc = (o0 < 256) ? o0 : o0 - 256;
            #pragma unroll
            for (int p = 0; p < 4; ++p) {
                const int idx = p * 256 + t, row = idx >> 3, ch = idx & 7;
                const unsigned* ls = (const unsigned*)&Ls[row * 136 + ch * 16];
                const uint4 a = *(const uint4*)ls;
                const uint4 b2 = *(const uint4*)(ls + 4);
                uint4 o;
                o.x = fp8x4(bflo(a.x), bfhi(a.x), bflo(a.y), bfhi(a.y));
                o.y = fp8x4(bflo(a.z), bfhi(a.z), bflo(a.w), bfhi(a.w));
                o.z = fp8x4(bflo(b2.x), bfhi(b2.x), bflo(b2.y), bfhi(b2.y));
                o.w = fp8x4(bflo(b2.z), bfhi(b2.z), bflo(b2.w), bfhi(b2.w));
                *(uint4*)(dst + ((size_t)b * NN + n0 + row) * 256 + oc + ch * 16) = o;
            }
        } else {
            #pragma unroll
            for (int fm = 0; fm < 4; ++fm)
                #pragma unroll
                for (int fn = 0; fn < 4; ++fn)
                    #pragma unroll
                    for (int r = 0; r < 4; ++r)
                        Ls[(wn * 64 + fn * 16 + lo) * 136 + wm * 64 + fm * 16 + hi * 4 + r] =
                            __float2bfloat16(acc[fm][fn][r] + bias[fn]);
            __syncthreads();
            #pragma unroll
            for (int p = 0; p < 8; ++p) {
                const int idx = p * 256 + t;
                const int ch = idx >> 7, cr = idx & 127;
                const unsigned* ls = (const unsigned*)&Ls[cr * 136 + ch * 8];
                const uint4 a = *(const uint4*)ls;
                uint2 o;
                o.x = fp8x4(bflo(a.x), bfhi(a.x), bflo(a.y), bfhi(a.y));
                o.y = fp8x4(bflo(a.z), bfhi(a.z), bflo(a.w), bfhi(a.w));
                const int g = (n0 >> 3) + ch;
                *(uint2*)(Vf8 + (((size_t)b * 128 + g) * 256 + (o0 - 512) + cr) * 8) = o;
            }
        }
        __syncthreads();   // Ls reads done before next ot's bstage overwrites
    }
}

// ---------------------------------------------------------------------------
// Kernel 2: flash attention — r14/r15 (fp8, counted-vmcnt pipeline), proven.
// ---------------------------------------------------------------------------
__device__ __forceinline__ void stage_tile(const unsigned char* __restrict__ Kb,
                                           const unsigned char* __restrict__ Vb,
                                           char* Kd, char* Vd, int m0, int t)
{
    {   // K: 512 x 16B units, 1 per thread
        const int row = t >> 4, pc = t & 15;
        const int prow = (row & 19) | ((row & 4) << 1) | ((row & 8) >> 1); // pi
        const int sc = pc ^ (row & 15);
        glds16(Kb + (size_t)(m0 + prow) * 256 + sc * 16, Kd + t * 16);
    }
    {   // V: pure linear 8KB copy (global layout matches LDS layout)
        glds16(Vb + (size_t)(m0 >> 3) * 2048 + t * 16, Vd + t * 16);
    }
}

__global__ __launch_bounds__(512, 2) void attn_kernel(
    const unsigned char* __restrict__ Qt8, const unsigned char* __restrict__ Kt8,
    const unsigned char* __restrict__ Vf8, const float* __restrict__ w_out,
    const float* __restrict__ b_out, const float* __restrict__ xg,
    float* __restrict__ out)
{
    __shared__ char smem[139264];   // loop: K 8x8K @0 | V 8x8K @65536

    const int t  = threadIdx.x;
    const int wv = t >> 6, ln = t & 63;
    const int l32 = ln & 31, h2 = ln >> 5;
    const int qgrp = wv & 3, half = wv >> 2;
    const int wid = blockIdx.x + 8 * blockIdx.y;
    const int swz = (wid & 7) * 32 + (wid >> 3);       // XCD gets 4 batches
    const int qb = swz & 7, b = swz >> 3;
    const int n0 = qb * 128;
    const float scale = 0.0625f;  // 1/sqrt(256)

    const unsigned char* Kbase = Kt8 + (size_t)b * NN * 256;
    const unsigned char* Vbase = Vf8 + (size_t)b * 128 * 2048;

    const unsigned char* qp = Qt8 + ((size_t)b * NN + n0 + qgrp * 32 + l32) * 256;
    i64 qf[16];
    #pragma unroll
    for (int ks = 0; ks < 16; ++ks)
        qf[ks] = *(const i64*)(qp + ks * 16 + h2 * 8);

    f32x16 acc[8];
    #pragma unroll
    for (int ct = 0; ct < 8; ++ct)
        #pragma unroll
        for (int r = 0; r < 16; ++r) acc[ct][r] = 0.f;
    float mr = 0.f;
    float sr = 0.f;

    #pragma unroll
    for (int tt = 0; tt < 4; ++tt)
        stage_tile(Kbase, Vbase, smem + tt * 8192,
                   smem + 65536 + tt * 8192, tt * 32, t);

    for (int s = 0; s < 16; ++s) {
        if (s < 14) {
            const int t2 = 2 * s + 4, t3 = 2 * s + 5;
            stage_tile(Kbase, Vbase, smem + (t2 & 7) * 8192,
                       smem + 65536 + (t2 & 7) * 8192, t2 * 32, t);
            stage_tile(Kbase, Vbase, smem + (t3 & 7) * 8192,
                       smem + 65536 + (t3 & 7) * 8192, t3 * 32, t);
        }
        if (s <= 13)      asm volatile("s_waitcnt vmcnt(8)" ::: "memory");
        else if (s == 14) asm volatile("s_waitcnt vmcnt(4)" ::: "memory");
        else              asm volatile("s_waitcnt vmcnt(0)" ::: "memory");
        __builtin_amdgcn_s_barrier();
        __builtin_amdgcn_sched_barrier(0);

        const int tile = 2 * s + half;
        char* const Kc = smem + (tile & 7) * 8192;
        char* const Vc = smem + 65536 + (tile & 7) * 8192;

        // QK(s): two independent 8-deep chains (fp8, K=16)
        f32x16 sfA, sfB;
        #pragma unroll
        for (int r = 0; r < 16; ++r) { sfA[r] = 0.f; sfB[r] = 0.f; }
        __builtin_amdgcn_s_setprio(1);
        #pragma unroll
        for (int ks = 0; ks < 8; ++ks) {
            const int pc = ks ^ (l32 & 15);
            const i64 kf = *(const i64*)(Kc + l32 * 256 + pc * 16 + h2 * 8);
            sfA = __builtin_amdgcn_mfma_f32_32x32x16_fp8_fp8(kf, qf[ks], sfA, 0, 0, 0);
        }
        #pragma unroll
        for (int ks = 8; ks < 16; ++ks) {
            const int pc = ks ^ (l32 & 15);
            const i64 kf = *(const i64*)(Kc + l32 * 256 + pc * 16 + h2 * 8);
            sfB = __builtin_amdgcn_mfma_f32_32x32x16_fp8_fp8(kf, qf[ks], sfB, 0, 0, 0);
        }
        __builtin_amdgcn_s_setprio(0);

        // softmax(s)
        float sv[16];
        #pragma unroll
        for (int r = 0; r < 16; ++r) sv[r] = sfA[r] + sfB[r];

        float m0a = fmaxf(sv[0], sv[1]),  m1a = fmaxf(sv[2], sv[3]);
        float m2a = fmaxf(sv[4], sv[5]),  m3a = fmaxf(sv[6], sv[7]);
        float m4a = fmaxf(sv[8], sv[9]),  m5a = fmaxf(sv[10], sv[11]);
        float m6a = fmaxf(sv[12], sv[13]), m7a = fmaxf(sv[14], sv[15]);
        float m0b = fmaxf(m0a, m1a), m1b = fmaxf(m2a, m3a);
        float m2b = fmaxf(m4a, m5a), m3b = fmaxf(m6a, m7a);
        float tm = fmaxf(fmaxf(m0b, m1b), fmaxf(m2b, m3b));
        tm = fmaxf(tm, __shfl_xor(tm, 32, 64));
        tm *= scale;
        if (__any(tm > mr + 8.f)) {
            const float mn = fmaxf(mr, tm);
            const float al = __expf(mr - mn);
            mr = mn;
            sr *= al;
            #pragma unroll
            for (int ct = 0; ct < 8; ++ct)
                #pragma unroll
                for (int r = 0; r < 16; ++r) acc[ct][r] *= al;
        }
        float p[16];
        #pragma unroll
        for (int r = 0; r < 16; ++r)
            p[r] = __expf(sv[r] * scale - mr);
        float s0a = p[0] + p[1],  s1a = p[2] + p[3];
        float s2a = p[4] + p[5],  s3a = p[6] + p[7];
        float s4a = p[8] + p[9],  s5a = p[10] + p[11];
        float s6a = p[12] + p[13], s7a = p[14] + p[15];
        float sacc = ((s0a + s1a) + (s2a + s3a)) + ((s4a + s5a) + (s6a + s7a));
        sacc += __shfl_xor(sacc, 32, 64);
        sr += sacc;

        // zero-shuffle PV B-frags (pi property)
        i64 pb[2];
        #pragma unroll
        for (int kstep = 0; kstep < 2; ++kstep) {
            union { unsigned u[2]; i64 l; } uu;
            uu.u[0] = fp8x4(p[8 * kstep + 0], p[8 * kstep + 1],
                            p[8 * kstep + 2], p[8 * kstep + 3]);
            uu.u[1] = fp8x4(p[8 * kstep + 4], p[8 * kstep + 5],
                            p[8 * kstep + 6], p[8 * kstep + 7]);
            pb[kstep] = uu.l;
        }

        // PV(s)
        __builtin_amdgcn_s_setprio(1);
        #pragma unroll
        for (int ct = 0; ct < 8; ++ct) {
            #pragma unroll
            for (int kstep = 0; kstep < 2; ++kstep) {
                const i64 vf = *(const i64*)(Vc + (2 * kstep + h2) * 2048 +
                                             (ct * 32 + l32) * 8);
                acc[ct] = __builtin_amdgcn_mfma_f32_32x32x16_fp8_fp8(vf, pb[kstep], acc[ct], 0, 0, 0);
            }
        }
        __builtin_amdgcn_s_setprio(0);
    }
    __syncthreads();   // all waves done reading K/V before ex overlay

    // ---- pair merge (2 phases) -> H bf16 in LDS ----
    float* const ex = (float*)smem;                              // 128 x 132 f32
    __hip_bfloat16* const Hld = (__hip_bfloat16*)(smem + 69632); // [128][264]
    #pragma unroll
    for (int ph = 0; ph < 2; ++ph) {
        if (half == 1 && (qgrp >> 1) == ph) {
            float* dst = ex + ((qgrp & 1) * 64 + ln) * 132;
            #pragma unroll
            for (int ct = 0; ct < 8; ++ct)
                #pragma unroll
                for (int rr = 0; rr < 4; ++rr) {
                    f32x4 v = {acc[ct][rr * 4 + 0], acc[ct][rr * 4 + 1],
                               acc[ct][rr * 4 + 2], acc[ct][rr * 4 + 3]};
                    *(f32x4*)(dst + ct * 16 + rr * 4) = v;
                }
            dst[128] = mr;
            dst[129] = sr;
        }
        __syncthreads();
        if (half == 0 && (qgrp >> 1) == ph) {
            const float* src = ex + ((qgrp & 1) * 64 + ln) * 132;
            const float mb = src[128], lb = src[129];
            const float m = fmaxf(mr, mb);
            float fa = __expf(mr - m), fb = __expf(mb - m);
            const float inv = 1.0f / (sr * fa + lb * fb);
            fa *= inv; fb *= inv;
            __hip_bfloat16* hrow = Hld + (size_t)(qgrp * 32 + l32) * 264;
            #pragma unroll
            for (int ct = 0; ct < 8; ++ct)
                #pragma unroll
                for (int ss = 0; ss < 4; ++ss) {
                    const float o0 = acc[ct][ss * 4 + 0] * fa + src[ct * 16 + ss * 4 + 0] * fb;
                    const float o1 = acc[ct][ss * 4 + 1] * fa + src[ct * 16 + ss * 4 + 1] * fb;
                    const float o2 = acc[ct][ss * 4 + 2] * fa + src[ct * 16 + ss * 4 + 2] * fb;
                    const float o3 = acc[ct][ss * 4 + 3] * fa + src[ct * 16 + ss * 4 + 3] * fb;
                    uint2 v;
                    v.x = pack2(o0, o1);
                    v.y = pack2(o2, o3);
                    *(uint2*)(hrow + ct * 32 + ss * 8 + h2 * 4) = v;
                }
        }
        __syncthreads();
    }

    // ---- fused output projection: out = W_out * H^T + b_out + x ----
    __hip_bfloat16* const Wld = (__hip_bfloat16*)smem;   // [128][264], over ex
    const int oT = wv >> 1;
    const int nT0 = (wv & 1) * 2, nT1 = nT0 + 1;
    for (int oh = 0; oh < 2; ++oh) {
        #pragma unroll
        for (int p = 0; p < 8; ++p) {
            const int idx = p * 512 + t;
            const int o = idx >> 5, ck = idx & 31;
            const float* wp = w_out + (size_t)(oh * 128 + o) * NC + ck * 8;
            const float4 u0 = *(const float4*)wp;
            const float4 u1 = *(const float4*)(wp + 4);
            uint4 pk;
            pk.x = pack2(u0.x, u0.y); pk.y = pack2(u0.z, u0.w);
            pk.z = pack2(u1.x, u1.y); pk.w = pack2(u1.z, u1.w);
            *(uint4*)((char*)Wld + (size_t)o * 528 + ck * 16) = pk;
        }
        __syncthreads();

        f32x16 oc0, oc1;
        #pragma unroll
        for (int r = 0; r < 16; ++r) { oc0[r] = 0.f; oc1[r] = 0.f; }
        __builtin_amdgcn_s_setprio(1);
        #pragma unroll
        for (int ks = 0; ks < 16; ++ks) {
            const int ck = ks * 2 + h2;
            bf16x8 wf = *(const bf16x8*)((char*)Wld + (size_t)(oT * 32 + l32) * 528 + ck * 16);
            bf16x8 hf0 = *(const bf16x8*)((char*)Hld + (size_t)(nT0 * 32 + l32) * 528 + ck * 16);
            bf16x8 hf1 = *(const bf16x8*)((char*)Hld + (size_t)(nT1 * 32 + l32) * 528 + ck * 16);
            oc0 = __builtin_amdgcn_mfma_f32_32x32x16_bf16(wf, hf0, oc0, 0, 0, 0);
            oc1 = __builtin_amdgcn_mfma_f32_32x32x16_bf16(wf, hf1, oc1, 0, 0, 0);
        }
        __builtin_amdgcn_s_setprio(0);

        #pragma unroll
        for (int r = 0; r < 16; ++r) {
            const int o = oh * 128 + oT * 32 + (r & 3) + 8 * (r >> 2) + 4 * h2;
            const float bo = b_out[o];
            const size_t rowg = ((size_t)b * NC + o) * NN + n0;
            const size_t g0 = rowg + nT0 * 32 + l32;
            const size_t g1 = rowg + nT1 * 32 + l32;
            out[g0] = oc0[r] + bo + xg[g0];
            out[g1] = oc1[r] + bo + xg[g1];
        }
        __syncthreads();   // W area reused next half
    }
}

// ---------------------------------------------------------------------------
extern "C" void kernel_launch(void* const* d_in, const int* in_sizes, int n_in,
                              void* d_out, int out_size, void* d_ws, size_t ws_size,
                              hipStream_t stream) {
    const float* x     = (const float*)d_in[0];
    const float* w_in  = (const float*)d_in[1];
    const float* b_in  = (const float*)d_in[2];
    const float* w_out = (const float*)d_in[3];
    const float* b_out = (const float*)d_in[4];
    float* out = (float*)d_out;

    if (ws_size < (size_t)24 * 1024 * 1024) return;  // fail loud
    char* ws = (char*)d_ws;
    unsigned char* Qt8 = (unsigned char*)(ws);                       // 8 MB
    unsigned char* Kt8 = (unsigned char*)(ws + ((size_t)8 << 20));   // 8 MB
    unsigned char* Vf8 = (unsigned char*)(ws + ((size_t)16 << 20));  // 8 MB

    qkv_panel_kernel<<<dim3(8, 2, 32), 256, 0, stream>>>(x, w_in, b_in, Qt8, Kt8, Vf8);
    attn_kernel<<<dim3(8, 32), 512, 0, stream>>>(Qt8, Kt8, Vf8, w_out, b_out, x, out);
}